// Round 4
// baseline (25527.449 us; speedup 1.0000x reference)
//
#include <hip/hip_runtime.h>
#include <hip/hip_bf16.h>

#define TSTEPS 127
#define NBLK 256
#define NVB 250      // 32000/128
#define MROWS 8128   // 127*64

typedef unsigned short u16;
typedef unsigned int u32;
typedef __attribute__((ext_vector_type(8))) short bf16x8;
typedef __attribute__((ext_vector_type(8))) unsigned short u16x8;
typedef __attribute__((ext_vector_type(4))) float f32x4;

__device__ __forceinline__ float us2f(u16 u){ union{float f;u32 i;}v; v.i=(u32)u<<16; return v.f; }
__device__ __forceinline__ u16 f2us(float f){ __hip_bfloat16 h=__float2bfloat16(f); u16 r; __builtin_memcpy(&r,&h,2); return r; }
__device__ __forceinline__ void split2(float x, u16& hi, u16& lo){
  u16 h = f2us(x); lo = f2us(x - us2f(h)); hi = h;
}

// fenced grid barrier: release add (wbl2) -> relaxed spin -> acquire load per wave (inv)
__device__ __forceinline__ void gbar(u32* cnt, int id){
  __syncthreads();
  if (threadIdx.x == 0){
    __hip_atomic_fetch_add(&cnt[id], 1u, __ATOMIC_RELEASE, __HIP_MEMORY_SCOPE_AGENT);
    while (__hip_atomic_load(&cnt[id], __ATOMIC_RELAXED, __HIP_MEMORY_SCOPE_AGENT) < (u32)NBLK)
      __builtin_amdgcn_s_sleep(8);
  }
  __syncthreads();
  (void)__hip_atomic_load(&cnt[id], __ATOMIC_ACQUIRE, __HIP_MEMORY_SCOPE_AGENT);
}

// ---------------- prep kernels ----------------
__global__ void p_wcat(const float* __restrict__ Watt, const float* __restrict__ Wu,
                       float* __restrict__ Wcat){
  int idx = blockIdx.x*256 + threadIdx.x;      // 2048*2048
  int n = idx >> 11, k = idx & 2047;
  Wcat[idx] = (n < 1024) ? Watt[idx] : Wu[(size_t)(n-1024)*3072 + k];
}

// WY: Y-part of Wih in j'-order (j' = jj*4+g, j = g*1024+jj), split hi/lo
__global__ void p_wy(const float* __restrict__ Wih, u16* __restrict__ WYh, u16* __restrict__ WYl){
  int k = blockIdx.x*256 + threadIdx.x;        // 512
  int rp = blockIdx.y;                         // 4096
  int j = (rp & 3)*1024 + (rp >> 2);
  float v = Wih[(size_t)j*1536 + 1024 + k];
  u16 hi, lo; split2(v, hi, lo);
  WYh[(size_t)rp*512 + k] = hi; WYl[(size_t)rp*512 + k] = lo;
}

__global__ void p_wuh(const float* __restrict__ Wu, u16* __restrict__ Wh, u16* __restrict__ Wl){
  int k = blockIdx.x*256 + threadIdx.x;        // 1024
  int j = blockIdx.y;                          // 1024
  float v = Wu[(size_t)j*3072 + 2048 + k];
  u16 hi, lo; split2(v, hi, lo);
  Wh[(size_t)j*1024 + k] = hi; Wl[(size_t)j*1024 + k] = lo;
}

__global__ void p_y(const int* __restrict__ ids, const float* __restrict__ Etgt,
                    u16* __restrict__ Yh, u16* __restrict__ Yl){
  int e0 = blockIdx.x*256 + threadIdx.x;       // 512
  int row = blockIdx.y;                        // 8192
  int id = ids[row];
  float v = Etgt[(size_t)id*512 + e0];
  u16 hi, lo; split2(v, hi, lo);
  Yh[(size_t)row*512 + e0] = hi; Yl[(size_t)row*512 + e0] = lo;
}

__global__ void p_wv(const float* __restrict__ Wv, u16* __restrict__ Wvb){
  size_t idx = (size_t)blockIdx.x*256 + threadIdx.x;  // 32000*1024
  Wvb[idx] = f2us(Wv[idx]);
}

__global__ void p_init(const float* __restrict__ h0,
                       u16* __restrict__ hhi, u16* __restrict__ hlo,
                       u16* __restrict__ ohi, u16* __restrict__ olo,
                       u32* __restrict__ cnt){
  int idx = blockIdx.x*256 + threadIdx.x;
  if (idx < 65536){
    float hv = h0[idx];
    u16 a, b; split2(hv, a, b); hhi[idx] = a; hlo[idx] = b;
    ohi[idx] = 0; olo[idx] = 0;
  } else if (idx < 66560){
    cnt[idx - 65536] = 0;
  }
}

// ---------------- enc_proj + Vu GEMM (fp32 in, bf16 out): M=16384 N=2048 K=2048 ----
union SharedU {
  struct { u16 a[128*72]; u16 b[128*72]; } st;
  float cc[128*128];
};

__global__ __launch_bounds__(256) void k_gemm32(
    const float* __restrict__ A, const float* __restrict__ Bm,
    const float* __restrict__ bias, u16* __restrict__ ep, u16* __restrict__ vu)
{
  __shared__ SharedU sm;
  const int tid = threadIdx.x;
  const int lane = tid & 63, w = tid >> 6;
  const int wm = w >> 1, wn = w & 1;
  int lw = blockIdx.y * gridDim.x + blockIdx.x;       // 2048
  int swz = (lw & 7)*256 + (lw >> 3);
  const int n0 = (swz & 15) * 128, m0 = (swz >> 4) * 128;
  f32x4 acc[4][4];
#pragma unroll
  for (int i=0;i<4;i++)
#pragma unroll
    for (int j=0;j<4;j++) acc[i][j] = (f32x4)(0.f);

  for (int k0 = 0; k0 < 2048; k0 += 64) {
    __syncthreads();
#pragma unroll
    for (int i=0;i<8;i++){
      int idx = tid + i*256;
      int r = idx >> 4, c4 = idx & 15;
      float4 va = *(const float4*)(&A[(size_t)(m0+r)*2048 + k0 + c4*4]);
      ushort4 sa; sa.x=f2us(va.x); sa.y=f2us(va.y); sa.z=f2us(va.z); sa.w=f2us(va.w);
      *(ushort4*)(&sm.st.a[r*72 + c4*4]) = sa;
      float4 vb = *(const float4*)(&Bm[(size_t)(n0+r)*2048 + k0 + c4*4]);
      ushort4 sb; sb.x=f2us(vb.x); sb.y=f2us(vb.y); sb.z=f2us(vb.z); sb.w=f2us(vb.w);
      *(ushort4*)(&sm.st.b[r*72 + c4*4]) = sb;
    }
    __syncthreads();
#pragma unroll
    for (int kk = 0; kk < 64; kk += 32) {
      bf16x8 af[4], bfr[4];
      int krow = kk + ((lane >> 4) << 3);
#pragma unroll
      for (int m4=0;m4<4;m4++)
        af[m4] = *(const bf16x8*)(&sm.st.a[(wm*64 + m4*16 + (lane & 15))*72 + krow]);
#pragma unroll
      for (int n4=0;n4<4;n4++)
        bfr[n4] = *(const bf16x8*)(&sm.st.b[(wn*64 + n4*16 + (lane & 15))*72 + krow]);
#pragma unroll
      for (int m4=0;m4<4;m4++)
#pragma unroll
        for (int n4=0;n4<4;n4++)
          acc[m4][n4] = __builtin_amdgcn_mfma_f32_16x16x32_bf16(af[m4], bfr[n4], acc[m4][n4], 0,0,0);
    }
  }
  __syncthreads();
#pragma unroll
  for (int m4=0;m4<4;m4++)
#pragma unroll
    for (int n4=0;n4<4;n4++)
#pragma unroll
      for (int i=0;i<4;i++){
        int row = wm*64 + m4*16 + ((lane>>4)<<2) + i;
        int col = wn*64 + n4*16 + (lane&15);
        sm.cc[row*128 + col] = acc[m4][n4][i];
      }
  __syncthreads();
  for (int idx = tid; idx < 128*128; idx += 256) {
    int row = idx >> 7, col = idx & 127;
    int gm = m0 + row, gn = n0 + col;
    float vv = sm.cc[idx];
    if (gn < 1024) { vv += bias[gn]; ep[(size_t)gm*1024 + gn] = f2us(vv); }
    else           { vu[(size_t)gm*1024 + (gn-1024)] = f2us(vv); }
  }
}

// ---------------- gY GEMM: gY[(t*64+b)][j'] = Y[t,b,:]·WY[j',:], split-bf16 ----
__global__ __launch_bounds__(256) void k_gy(
    const u16* __restrict__ Ah, const u16* __restrict__ Al,
    const u16* __restrict__ Bh, const u16* __restrict__ Bl,
    float* __restrict__ gY)
{
  __shared__ u16 sah[128*40], sal[128*40], sbh[128*40], sbl[128*40];
  const int tid = threadIdx.x;
  const int lane = tid & 63, w = tid >> 6;
  const int wm = w >> 1, wn = w & 1;
  const int l15 = lane & 15, q8 = (lane>>4)*8;
  int lw = blockIdx.y * gridDim.x + blockIdx.x;       // 2048
  int swz = (lw & 7)*256 + (lw >> 3);
  const int n0 = (swz & 31)*128, m0 = (swz >> 5)*128;
  f32x4 acc[4][4];
#pragma unroll
  for (int i=0;i<4;i++)
#pragma unroll
    for (int j=0;j<4;j++) acc[i][j] = (f32x4)(0.f);

  for (int k0 = 0; k0 < 512; k0 += 32){
    __syncthreads();
#pragma unroll
    for (int i=0;i<8;i++){
      int idx = i*256 + tid;          // 2048 = 4 mats x 512 u16x8
      int mat = idx >> 9, sub = idx & 511;
      int r = sub >> 2, c8 = (sub & 3)*8;
      const u16* src = (mat==0)?Ah:(mat==1)?Al:(mat==2)?Bh:Bl;
      size_t base = (mat<2 ? (size_t)(m0+r)*512 : (size_t)(n0+r)*512) + k0 + c8;
      u16x8 v = *(const u16x8*)(src + base);
      u16* dst = (mat==0)?sah:(mat==1)?sal:(mat==2)?sbh:sbl;
      *(u16x8*)(&dst[r*40 + c8]) = v;
    }
    __syncthreads();
    bf16x8 ah[4], al2[4], bh[4], bl2[4];
#pragma unroll
    for (int m4=0;m4<4;m4++){
      ah[m4]  = *(const bf16x8*)(&sah[(wm*64+m4*16+l15)*40 + q8]);
      al2[m4] = *(const bf16x8*)(&sal[(wm*64+m4*16+l15)*40 + q8]);
    }
#pragma unroll
    for (int n4=0;n4<4;n4++){
      bh[n4]  = *(const bf16x8*)(&sbh[(wn*64+n4*16+l15)*40 + q8]);
      bl2[n4] = *(const bf16x8*)(&sbl[(wn*64+n4*16+l15)*40 + q8]);
    }
#pragma unroll
    for (int m4=0;m4<4;m4++)
#pragma unroll
      for (int n4=0;n4<4;n4++){
        acc[m4][n4] = __builtin_amdgcn_mfma_f32_16x16x32_bf16(ah[m4],  bh[n4],  acc[m4][n4], 0,0,0);
        acc[m4][n4] = __builtin_amdgcn_mfma_f32_16x16x32_bf16(al2[m4], bh[n4],  acc[m4][n4], 0,0,0);
        acc[m4][n4] = __builtin_amdgcn_mfma_f32_16x16x32_bf16(ah[m4],  bl2[n4], acc[m4][n4], 0,0,0);
      }
  }
#pragma unroll
  for (int m4=0;m4<4;m4++)
#pragma unroll
    for (int n4=0;n4<4;n4++)
#pragma unroll
      for (int i=0;i<4;i++){
        int gm = m0 + wm*64 + m4*16 + ((lane>>4)<<2) + i;
        int gn = n0 + wn*64 + n4*16 + l15;
        gY[(size_t)gm*4096 + gn] = acc[m4][n4][i];
      }
}

// ---------------- persistent recurrence kernel ----------------
struct LoopShared {
  u16 wgh[16*2048];      // swizzled: byte ^= (row&7)<<4
  u16 wgl[16*2048];
  union {
    float gy[64*20];
    struct { float al[256]; float pared[4][256]; float red[8]; } p3;
  } u;
};

__global__ __launch_bounds__(256, 1) void k_loop(
    const float* __restrict__ Wih, const float* __restrict__ Whh,
    const float* __restrict__ c0g,
    const u16* __restrict__ Wuhh, const u16* __restrict__ Wuhl,
    const float* __restrict__ gY,
    const u16* __restrict__ ep, const u16* __restrict__ vuu,
    u16* __restrict__ hhi, u16* __restrict__ hlo,
    u16* __restrict__ ohi, u16* __restrict__ olo,
    float* __restrict__ ebuf, float* __restrict__ phB,
    u16* __restrict__ comb, u32* __restrict__ cnt)
{
  __shared__ LoopShared sh;
  const int tid = threadIdx.x, blk = blockIdx.x;
  const int lane = tid & 63, w = tid >> 6;
  const int l15 = lane & 15, q = lane >> 4;
  const int q8 = q * 8;
  const int bn = blk;

  // ---- one-time: load block's 16 j'-rows of [Wih_o | Whh] into LDS (split hi/lo) ----
  for (int i = tid; i < 16*512; i += 256){
    int r = i >> 9, c4 = i & 511;
    int jp = bn*16 + r;
    int j  = (jp & 3)*1024 + (jp >> 2);
    float4 v = (c4 < 256) ? *(const float4*)(&Wih[(size_t)j*1536 + c4*4])
                          : *(const float4*)(&Whh[(size_t)j*1024 + (c4-256)*4]);
    ushort4 hh, ll;
    split2(v.x, hh.x, ll.x); split2(v.y, hh.y, ll.y);
    split2(v.z, hh.z, ll.z); split2(v.w, hh.w, ll.w);
    int byteoff = (r*4096 + c4*8) ^ ((r & 7) << 4);
    *(ushort4*)((char*)sh.wgh + byteoff) = hh;
    *(ushort4*)((char*)sh.wgl + byteoff) = ll;
  }
  float cReg[4];
#pragma unroll
  for (int bt=0;bt<4;bt++)
    cReg[bt] = c0g[(size_t)(bt*16+l15)*1024 + bn*4 + q];
  __syncthreads();

  const char* wghc = (const char*)sh.wgh;
  const char* wglc = (const char*)sh.wgl;

  for (int t = 0; t < TSTEPS; ++t){
    const int p = t & 1;
    const u16* hhiP = hhi + p*65536;
    const u16* hloP = hlo + p*65536;
    u16* hhiN = hhi + (p^1)*65536;
    u16* hloN = hlo + (p^1)*65536;

    // ======== P1: gates MFMA (LDS weights) + lane-local LSTM ========
    {
      {
        const float* gsrc = gY + ((size_t)(t*64))*4096 + bn*16;
        int b = tid >> 2, c4 = tid & 3;
        float4 v = *(const float4*)(gsrc + (size_t)b*4096 + c4*4);
        *(float4*)(&sh.u.gy[b*20 + c4*4]) = v;
      }
      __syncthreads();
      f32x4 acc[4];
#pragma unroll
      for (int bt=0;bt<4;bt++){
#pragma unroll
        for (int i=0;i<4;i++)
          acc[bt][i] = sh.u.gy[(bt*16+l15)*20 + q*4 + i];
      }
#pragma unroll 2
      for (int kt=0; kt<32; ++kt){            // o_prev part (k 0..1024)
        int wb = (l15*4096 + kt*64 + q*16) ^ ((l15 & 7) << 4);
        bf16x8 wh = *(const bf16x8*)(wghc + wb);
        bf16x8 wl = *(const bf16x8*)(wglc + wb);
        int kg = kt*32 + q8;
        bf16x8 xh[4], xl[4];
#pragma unroll
        for (int bt=0;bt<4;bt++){
          size_t off = (size_t)(bt*16+l15)*1024 + kg;
          xh[bt] = *(const bf16x8*)(ohi + off);
          xl[bt] = *(const bf16x8*)(olo + off);
        }
#pragma unroll
        for (int bt=0;bt<4;bt++){
          acc[bt] = __builtin_amdgcn_mfma_f32_16x16x32_bf16(wh, xh[bt], acc[bt], 0,0,0);
          acc[bt] = __builtin_amdgcn_mfma_f32_16x16x32_bf16(wh, xl[bt], acc[bt], 0,0,0);
          acc[bt] = __builtin_amdgcn_mfma_f32_16x16x32_bf16(wl, xh[bt], acc[bt], 0,0,0);
        }
      }
#pragma unroll 2
      for (int kt=32; kt<64; ++kt){           // h part (k 1024..2048)
        int wb = (l15*4096 + kt*64 + q*16) ^ ((l15 & 7) << 4);
        bf16x8 wh = *(const bf16x8*)(wghc + wb);
        bf16x8 wl = *(const bf16x8*)(wglc + wb);
        int kg = (kt-32)*32 + q8;
        bf16x8 xh[4], xl[4];
#pragma unroll
        for (int bt=0;bt<4;bt++){
          size_t off = (size_t)(bt*16+l15)*1024 + kg;
          xh[bt] = *(const bf16x8*)(hhiP + off);
          xl[bt] = *(const bf16x8*)(hloP + off);
        }
#pragma unroll
        for (int bt=0;bt<4;bt++){
          acc[bt] = __builtin_amdgcn_mfma_f32_16x16x32_bf16(wh, xh[bt], acc[bt], 0,0,0);
          acc[bt] = __builtin_amdgcn_mfma_f32_16x16x32_bf16(wh, xl[bt], acc[bt], 0,0,0);
          acc[bt] = __builtin_amdgcn_mfma_f32_16x16x32_bf16(wl, xh[bt], acc[bt], 0,0,0);
        }
      }
      // lane-local LSTM: lane holds gates i,f,g,o for (b = bt*16+l15, jj = bn*4+q)
#pragma unroll
      for (int bt=0;bt<4;bt++){
        float gi = acc[bt][0], gf = acc[bt][1], gg = acc[bt][2], go = acc[bt][3];
        gi = 1.f/(1.f+expf(-gi));
        gf = 1.f/(1.f+expf(-gf));
        gg = tanhf(gg);
        go = 1.f/(1.f+expf(-go));
        float cn = gf*cReg[bt] + gi*gg;
        cReg[bt] = cn;
        float hv = go*tanhf(cn);
        u16 hh_, hl_; split2(hv, hh_, hl_);
        size_t off = (size_t)(bt*16+l15)*1024 + bn*4 + q;
        hhiN[off] = hh_; hloN[off] = hl_;
      }
    }
    gbar(cnt, t*3 + 0);

    // ======== P2: ph MFMA (blocks 0..15) | e_t (blocks 16..255) ========
    if (blk < 16){
      f32x4 pacc[4];
#pragma unroll
      for (int i=0;i<4;i++) pacc[i] = (f32x4)(0.f);
      const int jrow = blk*64 + w*16 + l15;
      const u16* bHp = Wuhh + (size_t)jrow*1024;
      const u16* bLp = Wuhl + (size_t)jrow*1024;
#pragma unroll 2
      for (int kt=0; kt<32; ++kt){
        int kg = kt*32 + q8;
        bf16x8 bh = *(const bf16x8*)(bHp + kg);
        bf16x8 bl = *(const bf16x8*)(bLp + kg);
        bf16x8 xh[4], xl[4];
#pragma unroll
        for (int m=0;m<4;m++){
          size_t off = (size_t)(m*16+l15)*1024 + kg;
          xh[m] = *(const bf16x8*)(hhiN + off);
          xl[m] = *(const bf16x8*)(hloN + off);
        }
#pragma unroll
        for (int m=0;m<4;m++){
          pacc[m] = __builtin_amdgcn_mfma_f32_16x16x32_bf16(xh[m], bh, pacc[m], 0,0,0);
          pacc[m] = __builtin_amdgcn_mfma_f32_16x16x32_bf16(xl[m], bh, pacc[m], 0,0,0);
          pacc[m] = __builtin_amdgcn_mfma_f32_16x16x32_bf16(xh[m], bl, pacc[m], 0,0,0);
        }
      }
#pragma unroll
      for (int m=0;m<4;m++)
#pragma unroll
        for (int i=0;i<4;i++){
          int b = m*16 + ((lane>>4)<<2) + i;
          phB[(size_t)b*1024 + jrow] = pacc[m][i];
        }
    } else {
      for (int u = blk - 16; u < 256; u += 240){
        const int b = u >> 2, sl = u & 3;
        // per-lane h slice k = l15*64 .. +64 (f32, hi+lo)
        float hreg[64];
        {
          const u16x8* hh = (const u16x8*)(hhiN + (size_t)b*1024 + l15*64);
          const u16x8* hl = (const u16x8*)(hloN + (size_t)b*1024 + l15*64);
#pragma unroll
          for (int j=0;j<8;j++){
            u16x8 a = hh[j], bb = hl[j];
#pragma unroll
            for (int e=0;e<8;e++) hreg[j*8+e] = us2f(a[e]) + us2f(bb[e]);
          }
        }
        const int rbase = sl*64 + w*16;
#pragma unroll
        for (int rg=0; rg<4; rg++){
          int s = rbase + rg*4 + q;
          const u16x8* row = (const u16x8*)(ep + ((size_t)(b*256 + s))*1024 + l15*64);
          float a = 0.f;
#pragma unroll
          for (int j=0;j<8;j++){
            u16x8 v = row[j];
#pragma unroll
            for (int e=0;e<8;e++) a += us2f(v[e]) * hreg[j*8+e];
          }
          a += __shfl_xor(a, 1); a += __shfl_xor(a, 2);
          a += __shfl_xor(a, 4); a += __shfl_xor(a, 8);
          if (l15 == 0) ebuf[b*256 + s] = a;
        }
      }
    }
    gbar(cnt, t*3 + 1);

    // ======== P3: softmax + pa + o_t (block = (b, jq)) ========
    {
      const int b = blk >> 2, jq = blk & 3;
      float x = ebuf[b*256 + tid];
      float m_ = x;
#pragma unroll
      for (int off=32; off; off>>=1) m_ = fmaxf(m_, __shfl_xor(m_, off));
      if (lane == 0) sh.u.p3.red[w] = m_;
      __syncthreads();
      m_ = fmaxf(fmaxf(sh.u.p3.red[0],sh.u.p3.red[1]), fmaxf(sh.u.p3.red[2],sh.u.p3.red[3]));
      float pv = expf(x - m_);
      float sv = pv;
#pragma unroll
      for (int off=32; off; off>>=1) sv += __shfl_xor(sv, off);
      if (lane == 0) sh.u.p3.red[4+w] = sv;
      __syncthreads();
      float tot = sh.u.p3.red[4]+sh.u.p3.red[5]+sh.u.p3.red[6]+sh.u.p3.red[7];
      sh.u.p3.al[tid] = pv / tot;
      __syncthreads();
      float a0=0.f, a1=0.f, a2=0.f, a3=0.f;
      const u16* vb = vuu + ((size_t)(b*256) + w*64)*1024 + jq*256 + lane*4;
      for (int s2=0; s2<64; s2++){
        float aa = sh.u.p3.al[w*64 + s2];
        ushort4 v = *(const ushort4*)(vb + (size_t)s2*1024);
        a0 += aa*us2f(v.x); a1 += aa*us2f(v.y); a2 += aa*us2f(v.z); a3 += aa*us2f(v.w);
      }
      float4 o4; o4.x=a0; o4.y=a1; o4.z=a2; o4.w=a3;
      *(float4*)(&sh.u.p3.pared[w][lane*4]) = o4;
      __syncthreads();
      if (tid < 64){
        const int col = tid*4;
        u16 his[4], los[4];
#pragma unroll
        for (int i=0;i<4;i++){
          float pa = sh.u.p3.pared[0][col+i] + sh.u.p3.pared[1][col+i]
                   + sh.u.p3.pared[2][col+i] + sh.u.p3.pared[3][col+i];
          pa += phB[(size_t)b*1024 + jq*256 + col + i];
          float o = tanhf(pa);
          split2(o, his[i], los[i]);
        }
        ushort4 vh; vh.x=his[0]; vh.y=his[1]; vh.z=his[2]; vh.w=his[3];
        ushort4 vl; vl.x=los[0]; vl.y=los[1]; vl.z=los[2]; vl.w=los[3];
        *(ushort4*)(ohi + (size_t)b*1024 + jq*256 + col) = vh;
        *(ushort4*)(olo + (size_t)b*1024 + jq*256 + col) = vl;
        *(ushort4*)(comb + (size_t)(t*64 + b)*1024 + jq*256 + col) = vh;
      }
    }
    gbar(cnt, t*3 + 2);
  }
}

// ---------------- vocab GEMM (bf16 in) + fused softmax partials ----------------
__global__ __launch_bounds__(256) void k_gemm16(
    const u16* __restrict__ A, const u16* __restrict__ Bm,
    const float* __restrict__ bias,
    float* __restrict__ pm, float* __restrict__ ps,
    float* __restrict__ gl, const int* __restrict__ ids)
{
  __shared__ SharedU sm;
  const int tid = threadIdx.x;
  const int lane = tid & 63, w = tid >> 6;
  const int wm = w >> 1, wn = w & 1;
  int lw = blockIdx.y * 250 + blockIdx.x;        // 16000
  int swz = (lw & 7)*2000 + (lw >> 3);
  const int n0 = (swz % 250) * 128, m0 = (swz / 250) * 128;
  f32x4 acc[4][4];
#pragma unroll
  for (int i=0;i<4;i++)
#pragma unroll
    for (int j=0;j<4;j++) acc[i][j] = (f32x4)(0.f);

  for (int k0 = 0; k0 < 1024; k0 += 64) {
    __syncthreads();
#pragma unroll
    for (int i=0;i<8;i++){
      int idx = i*256 + tid;
      int half = idx >> 10, id2 = idx & 1023;
      int r = id2 >> 3, c8 = (id2 & 7)*8;
      if (half == 0){
        int gm = m0 + r;
        u16x8 v = {0,0,0,0,0,0,0,0};
        if (gm < MROWS) v = *(const u16x8*)(A + (size_t)gm*1024 + k0 + c8);
        *(u16x8*)(&sm.st.a[r*72 + c8]) = v;
      } else {
        u16x8 v = *(const u16x8*)(Bm + (size_t)(n0 + r)*1024 + k0 + c8);
        *(u16x8*)(&sm.st.b[r*72 + c8]) = v;
      }
    }
    __syncthreads();
#pragma unroll
    for (int kk = 0; kk < 64; kk += 32) {
      bf16x8 af[4], bfr[4];
      int krow = kk + ((lane >> 4) << 3);
#pragma unroll
      for (int m4=0;m4<4;m4++)
        af[m4] = *(const bf16x8*)(&sm.st.a[(wm*64 + m4*16 + (lane & 15))*72 + krow]);
#pragma unroll
      for (int n4=0;n4<4;n4++)
        bfr[n4] = *(const bf16x8*)(&sm.st.b[(wn*64 + n4*16 + (lane & 15))*72 + krow]);
#pragma unroll
      for (int m4=0;m4<4;m4++)
#pragma unroll
        for (int n4=0;n4<4;n4++)
          acc[m4][n4] = __builtin_amdgcn_mfma_f32_16x16x32_bf16(af[m4], bfr[n4], acc[m4][n4], 0,0,0);
    }
  }
  __syncthreads();
#pragma unroll
  for (int m4=0;m4<4;m4++)
#pragma unroll
    for (int n4=0;n4<4;n4++)
#pragma unroll
      for (int i=0;i<4;i++){
        int row = wm*64 + m4*16 + ((lane>>4)<<2) + i;
        int col = wn*64 + n4*16 + (lane&15);
        sm.cc[row*128 + col] = acc[m4][n4][i];
      }
  __syncthreads();

  if (tid < 128) {
    int row = tid, gm = m0 + row;
    if (gm < MROWS) {
      float mx = -1e30f;
      for (int j=0;j<128;j++){
        int col = (row + j) & 127;
        float x = sm.cc[row*128+col] + bias[n0+col];
        mx = fmaxf(mx, x);
      }
      float sum = 0.f;
      for (int j=0;j<128;j++){
        int col = (row + j) & 127;
        float x = sm.cc[row*128+col] + bias[n0+col];
        sum += expf(x - mx);
      }
      pm[(size_t)gm*NVB + n0/128] = mx;
      ps[(size_t)gm*NVB + n0/128] = sum;
      int g = ids[gm + 64];
      unsigned d = (unsigned)(g - n0);
      if (d < 128u) gl[gm] = sm.cc[row*128 + (int)d] + bias[g];
    }
  }
}

// ---------------- final reduce ----------------
__global__ void k_reduce(const float* __restrict__ pm, const float* __restrict__ ps,
                         const float* __restrict__ gl, const int* __restrict__ ids,
                         float* __restrict__ out)
{
  int b = blockIdx.x, tid = threadIdx.x;
  int lane = tid & 63, w = tid >> 6;
  __shared__ float wacc[4];
  float accum = 0.f;
  for (int t = w; t < TSTEPS; t += 4) {
    int r = t*64 + b;
    const float* pmr = pm + (size_t)r*NVB;
    const float* psr = ps + (size_t)r*NVB;
    float mx = -1e30f;
    for (int p2 = lane; p2 < NVB; p2 += 64) mx = fmaxf(mx, pmr[p2]);
#pragma unroll
    for (int off=32; off; off>>=1) mx = fmaxf(mx, __shfl_xor(mx, off));
    float sm = 0.f;
    for (int p2 = lane; p2 < NVB; p2 += 64) sm += psr[p2] * expf(pmr[p2] - mx);
#pragma unroll
    for (int off=32; off; off>>=1) sm += __shfl_xor(sm, off);
    if (lane == 0) {
      int g = ids[r + 64];
      if (g != 0) accum += gl[r] - (mx + logf(sm));
    }
  }
  if (lane == 0) wacc[w] = accum;
  __syncthreads();
  if (tid == 0) out[b] = wacc[0]+wacc[1]+wacc[2]+wacc[3];
}

// ---------------- host ----------------
extern "C" void kernel_launch(void* const* d_in, const int* in_sizes, int n_in,
                              void* d_out, int out_size, void* d_ws, size_t ws_size,
                              hipStream_t stream)
{
  const int*   ids  = (const int*)d_in[0];
  const float* vc   = (const float*)d_in[1];
  const float* h0   = (const float*)d_in[2];
  const float* c0   = (const float*)d_in[3];
  const float* Etgt = (const float*)d_in[4];
  const float* Watt = (const float*)d_in[5];
  const float* batt = (const float*)d_in[6];
  const float* Wih  = (const float*)d_in[7];
  const float* Whh  = (const float*)d_in[8];
  const float* Wu   = (const float*)d_in[9];
  const float* Wv   = (const float*)d_in[10];
  const float* bv   = (const float*)d_in[11];
  float* out = (float*)d_out;

  char* p = (char*)d_ws;
  auto alloc = [&](size_t bytes)->char* {
    char* r = p; p += (bytes + 255) & ~(size_t)255; return r;
  };
  u32* cnt   = (u32*)alloc(4096);
  u16* Yh    = (u16*)alloc((size_t)8192*512*2);
  u16* Yl    = (u16*)alloc((size_t)8192*512*2);
  u16* WYh   = (u16*)alloc((size_t)4096*512*2);
  u16* WYl   = (u16*)alloc((size_t)4096*512*2);
  u16* Wuhh  = (u16*)alloc((size_t)1024*1024*2);
  u16* Wuhl  = (u16*)alloc((size_t)1024*1024*2);
  float* Wcat= (float*)alloc((size_t)2048*2048*4);
  u16* ep    = (u16*)alloc((size_t)64*256*1024*2);
  u16* vuu   = (u16*)alloc((size_t)64*256*1024*2);
  u16* Wvb   = (u16*)alloc((size_t)32000*1024*2);
  u16* comb  = (u16*)alloc((size_t)8192*1024*2);
  float* gY  = (float*)alloc((size_t)8192*4096*4);
  u16* hhi   = (u16*)alloc((size_t)2*65536*2);
  u16* hlo   = (u16*)alloc((size_t)2*65536*2);
  u16* ohi   = (u16*)alloc(65536*2);
  u16* olo   = (u16*)alloc(65536*2);
  float* ebuf= (float*)alloc((size_t)64*256*4);
  float* phB = (float*)alloc((size_t)64*1024*4);
  float* pm  = (float*)alloc((size_t)MROWS*NVB*4);
  float* ps  = (float*)alloc((size_t)MROWS*NVB*4);
  float* gl  = (float*)alloc((size_t)MROWS*4);

  p_init<<<260, 256, 0, stream>>>(h0, hhi, hlo, ohi, olo, cnt);
  p_wcat<<<(2048*2048)/256, 256, 0, stream>>>(Watt, Wu, Wcat);
  p_wy<<<dim3(2, 4096), 256, 0, stream>>>(Wih, WYh, WYl);
  p_wuh<<<dim3(4, 1024), 256, 0, stream>>>(Wu, Wuhh, Wuhl);
  p_y<<<dim3(2, 8192), 256, 0, stream>>>(ids, Etgt, Yh, Yl);
  p_wv<<<(32000*1024)/256, 256, 0, stream>>>(Wv, Wvb);

  k_gemm32<<<dim3(16, 128), 256, 0, stream>>>(vc, Wcat, batt, ep, vuu);
  k_gy<<<dim3(32, 64), 256, 0, stream>>>(Yh, Yl, WYh, WYl, gY);

  k_loop<<<NBLK, 256, 0, stream>>>(Wih, Whh, c0, Wuhh, Wuhl, gY, ep, vuu,
                                   hhi, hlo, ohi, olo, ebuf, phB, comb, cnt);

  k_gemm16<<<dim3(NVB, 64), 256, 0, stream>>>(comb, Wvb, bv, pm, ps, gl, ids);
  k_reduce<<<64, 256, 0, stream>>>(pm, ps, gl, ids, out);
}

// Round 5
// 16927.489 us; speedup vs baseline: 1.5080x; 1.5080x over previous
//
#include <hip/hip_runtime.h>
#include <hip/hip_bf16.h>

#define TSTEPS 127
#define NBLK 256
#define NVB 250      // 32000/128
#define MROWS 8128   // 127*64

typedef unsigned short u16;
typedef unsigned int u32;
typedef __attribute__((ext_vector_type(8))) short bf16x8;
typedef __attribute__((ext_vector_type(8))) unsigned short u16x8;
typedef __attribute__((ext_vector_type(4))) float f32x4;

__device__ __forceinline__ float us2f(u16 u){ union{float f;u32 i;}v; v.i=(u32)u<<16; return v.f; }
__device__ __forceinline__ u16 f2us(float f){ __hip_bfloat16 h=__float2bfloat16(f); u16 r; __builtin_memcpy(&r,&h,2); return r; }
__device__ __forceinline__ void split2(float x, u16& hi, u16& lo){
  u16 h = f2us(x); lo = f2us(x - us2f(h)); hi = h;
}

// ---- flag-array grid barrier: no RMW contention ----
// block i release-stores token to flags[i*32]; thread tid spins on flags[tid*32];
// per-wave acquire load afterwards invalidates L1/L2 for cross-XCD visibility.
__device__ __forceinline__ void gbar(u32* flags, u32 token){
  __syncthreads();   // compiler drains vmcnt for all waves before s_barrier
  if (threadIdx.x == 0)
    __hip_atomic_store(&flags[blockIdx.x*32], token, __ATOMIC_RELEASE, __HIP_MEMORY_SCOPE_AGENT);
  u32* myf = &flags[threadIdx.x*32];
  while (__hip_atomic_load(myf, __ATOMIC_RELAXED, __HIP_MEMORY_SCOPE_AGENT) < token)
    __builtin_amdgcn_s_sleep(1);
  __syncthreads();
  (void)__hip_atomic_load(&flags[blockIdx.x*32], __ATOMIC_ACQUIRE, __HIP_MEMORY_SCOPE_AGENT);
}

// ---------------- prep kernels ----------------
__global__ void p_wcat(const float* __restrict__ Watt, const float* __restrict__ Wu,
                       float* __restrict__ Wcat){
  int idx = blockIdx.x*256 + threadIdx.x;      // 2048*2048
  int n = idx >> 11, k = idx & 2047;
  Wcat[idx] = (n < 1024) ? Watt[idx] : Wu[(size_t)(n-1024)*3072 + k];
}

// WY: Y-part of Wih in j'-order (j' = jj*4+g, j = g*1024+jj), split hi/lo
__global__ void p_wy(const float* __restrict__ Wih, u16* __restrict__ WYh, u16* __restrict__ WYl){
  int k = blockIdx.x*256 + threadIdx.x;        // 512
  int rp = blockIdx.y;                         // 4096
  int j = (rp & 3)*1024 + (rp >> 2);
  float v = Wih[(size_t)j*1536 + 1024 + k];
  u16 hi, lo; split2(v, hi, lo);
  WYh[(size_t)rp*512 + k] = hi; WYl[(size_t)rp*512 + k] = lo;
}

__global__ void p_wuh(const float* __restrict__ Wu, u16* __restrict__ Wh, u16* __restrict__ Wl){
  int k = blockIdx.x*256 + threadIdx.x;        // 1024
  int j = blockIdx.y;                          // 1024
  float v = Wu[(size_t)j*3072 + 2048 + k];
  u16 hi, lo; split2(v, hi, lo);
  Wh[(size_t)j*1024 + k] = hi; Wl[(size_t)j*1024 + k] = lo;
}

__global__ void p_y(const int* __restrict__ ids, const float* __restrict__ Etgt,
                    u16* __restrict__ Yh, u16* __restrict__ Yl){
  int e0 = blockIdx.x*256 + threadIdx.x;       // 512
  int row = blockIdx.y;                        // 8192
  int id = ids[row];
  float v = Etgt[(size_t)id*512 + e0];
  u16 hi, lo; split2(v, hi, lo);
  Yh[(size_t)row*512 + e0] = hi; Yl[(size_t)row*512 + e0] = lo;
}

__global__ void p_wv(const float* __restrict__ Wv, u16* __restrict__ Wvb){
  size_t idx = (size_t)blockIdx.x*256 + threadIdx.x;  // 32000*1024
  Wvb[idx] = f2us(Wv[idx]);
}

__global__ void p_init(const float* __restrict__ h0,
                       u16* __restrict__ hhi, u16* __restrict__ hlo,
                       u16* __restrict__ ohi, u16* __restrict__ olo,
                       u32* __restrict__ cnt){
  int idx = blockIdx.x*256 + threadIdx.x;
  if (idx < 65536){
    float hv = h0[idx];
    u16 a, b; split2(hv, a, b); hhi[idx] = a; hlo[idx] = b;
    ohi[idx] = 0; olo[idx] = 0;
  } else if (idx < 65536 + 8192){
    cnt[idx - 65536] = 0;
  }
}

// ---------------- enc_proj + Vu GEMM (fp32 in, bf16 out): M=16384 N=2048 K=2048 ----
union SharedU {
  struct { u16 a[128*72]; u16 b[128*72]; } st;
  float cc[128*128];
};

__global__ __launch_bounds__(256) void k_gemm32(
    const float* __restrict__ A, const float* __restrict__ Bm,
    const float* __restrict__ bias, u16* __restrict__ ep, u16* __restrict__ vu)
{
  __shared__ SharedU sm;
  const int tid = threadIdx.x;
  const int lane = tid & 63, w = tid >> 6;
  const int wm = w >> 1, wn = w & 1;
  int lw = blockIdx.y * gridDim.x + blockIdx.x;       // 2048
  int swz = (lw & 7)*256 + (lw >> 3);
  const int n0 = (swz & 15) * 128, m0 = (swz >> 4) * 128;
  f32x4 acc[4][4];
#pragma unroll
  for (int i=0;i<4;i++)
#pragma unroll
    for (int j=0;j<4;j++) acc[i][j] = (f32x4)(0.f);

  for (int k0 = 0; k0 < 2048; k0 += 64) {
    __syncthreads();
#pragma unroll
    for (int i=0;i<8;i++){
      int idx = tid + i*256;
      int r = idx >> 4, c4 = idx & 15;
      float4 va = *(const float4*)(&A[(size_t)(m0+r)*2048 + k0 + c4*4]);
      ushort4 sa; sa.x=f2us(va.x); sa.y=f2us(va.y); sa.z=f2us(va.z); sa.w=f2us(va.w);
      *(ushort4*)(&sm.st.a[r*72 + c4*4]) = sa;
      float4 vb = *(const float4*)(&Bm[(size_t)(n0+r)*2048 + k0 + c4*4]);
      ushort4 sb; sb.x=f2us(vb.x); sb.y=f2us(vb.y); sb.z=f2us(vb.z); sb.w=f2us(vb.w);
      *(ushort4*)(&sm.st.b[r*72 + c4*4]) = sb;
    }
    __syncthreads();
#pragma unroll
    for (int kk = 0; kk < 64; kk += 32) {
      bf16x8 af[4], bfr[4];
      int krow = kk + ((lane >> 4) << 3);
#pragma unroll
      for (int m4=0;m4<4;m4++)
        af[m4] = *(const bf16x8*)(&sm.st.a[(wm*64 + m4*16 + (lane & 15))*72 + krow]);
#pragma unroll
      for (int n4=0;n4<4;n4++)
        bfr[n4] = *(const bf16x8*)(&sm.st.b[(wn*64 + n4*16 + (lane & 15))*72 + krow]);
#pragma unroll
      for (int m4=0;m4<4;m4++)
#pragma unroll
        for (int n4=0;n4<4;n4++)
          acc[m4][n4] = __builtin_amdgcn_mfma_f32_16x16x32_bf16(af[m4], bfr[n4], acc[m4][n4], 0,0,0);
    }
  }
  __syncthreads();
#pragma unroll
  for (int m4=0;m4<4;m4++)
#pragma unroll
    for (int n4=0;n4<4;n4++)
#pragma unroll
      for (int i=0;i<4;i++){
        int row = wm*64 + m4*16 + ((lane>>4)<<2) + i;
        int col = wn*64 + n4*16 + (lane&15);
        sm.cc[row*128 + col] = acc[m4][n4][i];
      }
  __syncthreads();
  for (int idx = tid; idx < 128*128; idx += 256) {
    int row = idx >> 7, col = idx & 127;
    int gm = m0 + row, gn = n0 + col;
    float vv = sm.cc[idx];
    if (gn < 1024) { vv += bias[gn]; ep[(size_t)gm*1024 + gn] = f2us(vv); }
    else           { vu[(size_t)gm*1024 + (gn-1024)] = f2us(vv); }
  }
}

// ---------------- gY GEMM: gY[(t*64+b)][j'] = Y[t,b,:]·WY[j',:], split-bf16 ----
__global__ __launch_bounds__(256) void k_gy(
    const u16* __restrict__ Ah, const u16* __restrict__ Al,
    const u16* __restrict__ Bh, const u16* __restrict__ Bl,
    float* __restrict__ gY)
{
  __shared__ u16 sah[128*40], sal[128*40], sbh[128*40], sbl[128*40];
  const int tid = threadIdx.x;
  const int lane = tid & 63, w = tid >> 6;
  const int wm = w >> 1, wn = w & 1;
  const int l15 = lane & 15, q8 = (lane>>4)*8;
  int lw = blockIdx.y * gridDim.x + blockIdx.x;       // 2048
  int swz = (lw & 7)*256 + (lw >> 3);
  const int n0 = (swz & 31)*128, m0 = (swz >> 5)*128;
  f32x4 acc[4][4];
#pragma unroll
  for (int i=0;i<4;i++)
#pragma unroll
    for (int j=0;j<4;j++) acc[i][j] = (f32x4)(0.f);

  for (int k0 = 0; k0 < 512; k0 += 32){
    __syncthreads();
#pragma unroll
    for (int i=0;i<8;i++){
      int idx = i*256 + tid;          // 2048 = 4 mats x 512 u16x8
      int mat = idx >> 9, sub = idx & 511;
      int r = sub >> 2, c8 = (sub & 3)*8;
      const u16* src = (mat==0)?Ah:(mat==1)?Al:(mat==2)?Bh:Bl;
      size_t base = (mat<2 ? (size_t)(m0+r)*512 : (size_t)(n0+r)*512) + k0 + c8;
      u16x8 v = *(const u16x8*)(src + base);
      u16* dst = (mat==0)?sah:(mat==1)?sal:(mat==2)?sbh:sbl;
      *(u16x8*)(&dst[r*40 + c8]) = v;
    }
    __syncthreads();
    bf16x8 ah[4], al2[4], bh[4], bl2[4];
#pragma unroll
    for (int m4=0;m4<4;m4++){
      ah[m4]  = *(const bf16x8*)(&sah[(wm*64+m4*16+l15)*40 + q8]);
      al2[m4] = *(const bf16x8*)(&sal[(wm*64+m4*16+l15)*40 + q8]);
    }
#pragma unroll
    for (int n4=0;n4<4;n4++){
      bh[n4]  = *(const bf16x8*)(&sbh[(wn*64+n4*16+l15)*40 + q8]);
      bl2[n4] = *(const bf16x8*)(&sbl[(wn*64+n4*16+l15)*40 + q8]);
    }
#pragma unroll
    for (int m4=0;m4<4;m4++)
#pragma unroll
      for (int n4=0;n4<4;n4++){
        acc[m4][n4] = __builtin_amdgcn_mfma_f32_16x16x32_bf16(ah[m4],  bh[n4],  acc[m4][n4], 0,0,0);
        acc[m4][n4] = __builtin_amdgcn_mfma_f32_16x16x32_bf16(al2[m4], bh[n4],  acc[m4][n4], 0,0,0);
        acc[m4][n4] = __builtin_amdgcn_mfma_f32_16x16x32_bf16(ah[m4],  bl2[n4], acc[m4][n4], 0,0,0);
      }
  }
#pragma unroll
  for (int m4=0;m4<4;m4++)
#pragma unroll
    for (int n4=0;n4<4;n4++)
#pragma unroll
      for (int i=0;i<4;i++){
        int gm = m0 + wm*64 + m4*16 + ((lane>>4)<<2) + i;
        int gn = n0 + wn*64 + n4*16 + l15;
        gY[(size_t)gm*4096 + gn] = acc[m4][n4][i];
      }
}

// ---------------- persistent recurrence kernel ----------------
struct LoopShared {
  u16 wgh[16*2048];      // swizzled: byte ^= (row&7)<<4
  u16 wgl[16*2048];
  union {
    float gy[64*20];
    struct { float al[256]; float pared[4][256]; float red[8]; } p3;
  } u;
};

__global__ __launch_bounds__(256, 1) void k_loop(
    const float* __restrict__ Wih, const float* __restrict__ Whh,
    const float* __restrict__ c0g,
    const u16* __restrict__ Wuhh, const u16* __restrict__ Wuhl,
    const float* __restrict__ gY,
    const u16* __restrict__ ep, const u16* __restrict__ vuu,
    u16* __restrict__ hhi, u16* __restrict__ hlo,
    u16* __restrict__ ohi, u16* __restrict__ olo,
    float* __restrict__ ebuf, float* __restrict__ phB,
    u16* __restrict__ comb, u32* __restrict__ cnt)
{
  __shared__ LoopShared sh;
  const int tid = threadIdx.x, blk = blockIdx.x;
  const int lane = tid & 63, w = tid >> 6;
  const int l15 = lane & 15, q = lane >> 4;
  const int q8 = q * 8;
  const int bn = blk;

  // ---- one-time: load block's 16 j'-rows of [Wih_o | Whh] into LDS (split hi/lo) ----
  for (int i = tid; i < 16*512; i += 256){
    int r = i >> 9, c4 = i & 511;
    int jp = bn*16 + r;
    int j  = (jp & 3)*1024 + (jp >> 2);
    float4 v = (c4 < 256) ? *(const float4*)(&Wih[(size_t)j*1536 + c4*4])
                          : *(const float4*)(&Whh[(size_t)j*1024 + (c4-256)*4]);
    ushort4 hh, ll;
    split2(v.x, hh.x, ll.x); split2(v.y, hh.y, ll.y);
    split2(v.z, hh.z, ll.z); split2(v.w, hh.w, ll.w);
    int byteoff = (r*4096 + c4*8) ^ ((r & 7) << 4);
    *(ushort4*)((char*)sh.wgh + byteoff) = hh;
    *(ushort4*)((char*)sh.wgl + byteoff) = ll;
  }
  // wave w owns bt = w: c for (b = w*16+l15, jj = bn*4+q)
  float cReg = c0g[(size_t)(w*16+l15)*1024 + bn*4 + q];
  __syncthreads();

  const char* wghc = (const char*)sh.wgh;
  const char* wglc = (const char*)sh.wgl;

  for (int t = 0; t < TSTEPS; ++t){
    const int p = t & 1;
    const u16* hhiP = hhi + p*65536;
    const u16* hloP = hlo + p*65536;
    u16* hhiN = hhi + (p^1)*65536;
    u16* hloN = hlo + (p^1)*65536;

    // ======== P1: gates MFMA (LDS weights, wave w owns bt=w) + lane-local LSTM ========
    {
      {
        const float* gsrc = gY + ((size_t)(t*64))*4096 + bn*16;
        int b = tid >> 2, c4 = tid & 3;
        float4 v = *(const float4*)(gsrc + (size_t)b*4096 + c4*4);
        *(float4*)(&sh.u.gy[b*20 + c4*4]) = v;
      }
      __syncthreads();
      f32x4 acc;
#pragma unroll
      for (int i=0;i<4;i++)
        acc[i] = sh.u.gy[(w*16+l15)*20 + q*4 + i];
#pragma unroll 2
      for (int kt=0; kt<32; ++kt){            // o_prev part (k 0..1024)
        int wb = (l15*4096 + kt*64 + q*16) ^ ((l15 & 7) << 4);
        bf16x8 wh = *(const bf16x8*)(wghc + wb);
        bf16x8 wl = *(const bf16x8*)(wglc + wb);
        int kg = kt*32 + q8;
        size_t off = (size_t)(w*16+l15)*1024 + kg;
        bf16x8 xh = *(const bf16x8*)(ohi + off);
        bf16x8 xl = *(const bf16x8*)(olo + off);
        acc = __builtin_amdgcn_mfma_f32_16x16x32_bf16(wh, xh, acc, 0,0,0);
        acc = __builtin_amdgcn_mfma_f32_16x16x32_bf16(wh, xl, acc, 0,0,0);
        acc = __builtin_amdgcn_mfma_f32_16x16x32_bf16(wl, xh, acc, 0,0,0);
      }
#pragma unroll 2
      for (int kt=32; kt<64; ++kt){           // h part (k 1024..2048)
        int wb = (l15*4096 + kt*64 + q*16) ^ ((l15 & 7) << 4);
        bf16x8 wh = *(const bf16x8*)(wghc + wb);
        bf16x8 wl = *(const bf16x8*)(wglc + wb);
        int kg = (kt-32)*32 + q8;
        size_t off = (size_t)(w*16+l15)*1024 + kg;
        bf16x8 xh = *(const bf16x8*)(hhiP + off);
        bf16x8 xl = *(const bf16x8*)(hloP + off);
        acc = __builtin_amdgcn_mfma_f32_16x16x32_bf16(wh, xh, acc, 0,0,0);
        acc = __builtin_amdgcn_mfma_f32_16x16x32_bf16(wh, xl, acc, 0,0,0);
        acc = __builtin_amdgcn_mfma_f32_16x16x32_bf16(wl, xh, acc, 0,0,0);
      }
      // lane-local LSTM: lane holds gates i,f,g,o for (b = w*16+l15, jj = bn*4+q)
      {
        float gi = acc[0], gf = acc[1], gg = acc[2], go = acc[3];
        gi = 1.f/(1.f+expf(-gi));
        gf = 1.f/(1.f+expf(-gf));
        gg = tanhf(gg);
        go = 1.f/(1.f+expf(-go));
        float cn = gf*cReg + gi*gg;
        cReg = cn;
        float hv = go*tanhf(cn);
        u16 hh_, hl_; split2(hv, hh_, hl_);
        size_t off = (size_t)(w*16+l15)*1024 + bn*4 + q;
        hhiN[off] = hh_; hloN[off] = hl_;
      }
    }
    gbar(cnt, (u32)(t*3 + 1));

    // ======== P2: ph MFMA (blocks 0..15) | e_t (blocks 16..255) ========
    if (blk < 16){
      f32x4 pacc[4];
#pragma unroll
      for (int i=0;i<4;i++) pacc[i] = (f32x4)(0.f);
      const int jrow = blk*64 + w*16 + l15;
      const u16* bHp = Wuhh + (size_t)jrow*1024;
      const u16* bLp = Wuhl + (size_t)jrow*1024;
#pragma unroll 2
      for (int kt=0; kt<32; ++kt){
        int kg = kt*32 + q8;
        bf16x8 bh = *(const bf16x8*)(bHp + kg);
        bf16x8 bl = *(const bf16x8*)(bLp + kg);
        bf16x8 xh[4], xl[4];
#pragma unroll
        for (int m=0;m<4;m++){
          size_t off = (size_t)(m*16+l15)*1024 + kg;
          xh[m] = *(const bf16x8*)(hhiN + off);
          xl[m] = *(const bf16x8*)(hloN + off);
        }
#pragma unroll
        for (int m=0;m<4;m++){
          pacc[m] = __builtin_amdgcn_mfma_f32_16x16x32_bf16(xh[m], bh, pacc[m], 0,0,0);
          pacc[m] = __builtin_amdgcn_mfma_f32_16x16x32_bf16(xl[m], bh, pacc[m], 0,0,0);
          pacc[m] = __builtin_amdgcn_mfma_f32_16x16x32_bf16(xh[m], bl, pacc[m], 0,0,0);
        }
      }
#pragma unroll
      for (int m=0;m<4;m++)
#pragma unroll
        for (int i=0;i<4;i++){
          int b = m*16 + ((lane>>4)<<2) + i;
          phB[(size_t)b*1024 + jrow] = pacc[m][i];
        }
    } else {
      for (int u = blk - 16; u < 256; u += 240){
        const int b = u >> 2, sl = u & 3;
        // per-lane h slice k = l15*64 .. +64 (f32, hi+lo)
        float hreg[64];
        {
          const u16x8* hh = (const u16x8*)(hhiN + (size_t)b*1024 + l15*64);
          const u16x8* hl = (const u16x8*)(hloN + (size_t)b*1024 + l15*64);
#pragma unroll
          for (int j=0;j<8;j++){
            u16x8 a = hh[j], bb = hl[j];
#pragma unroll
            for (int e=0;e<8;e++) hreg[j*8+e] = us2f(a[e]) + us2f(bb[e]);
          }
        }
        const int rbase = sl*64 + w*16;
#pragma unroll
        for (int rg=0; rg<4; rg++){
          int s = rbase + rg*4 + q;
          const u16x8* row = (const u16x8*)(ep + ((size_t)(b*256 + s))*1024 + l15*64);
          float a = 0.f;
#pragma unroll
          for (int j=0;j<8;j++){
            u16x8 v = row[j];
#pragma unroll
            for (int e=0;e<8;e++) a += us2f(v[e]) * hreg[j*8+e];
          }
          a += __shfl_xor(a, 1); a += __shfl_xor(a, 2);
          a += __shfl_xor(a, 4); a += __shfl_xor(a, 8);
          if (l15 == 0) ebuf[b*256 + s] = a;
        }
      }
    }
    gbar(cnt, (u32)(t*3 + 2));

    // ======== P3: softmax + pa + o_t (block = (b, jq)) ========
    {
      const int b = blk >> 2, jq = blk & 3;
      float x = ebuf[b*256 + tid];
      float m_ = x;
#pragma unroll
      for (int off=32; off; off>>=1) m_ = fmaxf(m_, __shfl_xor(m_, off));
      if (lane == 0) sh.u.p3.red[w] = m_;
      __syncthreads();
      m_ = fmaxf(fmaxf(sh.u.p3.red[0],sh.u.p3.red[1]), fmaxf(sh.u.p3.red[2],sh.u.p3.red[3]));
      float pv = expf(x - m_);
      float sv = pv;
#pragma unroll
      for (int off=32; off; off>>=1) sv += __shfl_xor(sv, off);
      if (lane == 0) sh.u.p3.red[4+w] = sv;
      __syncthreads();
      float tot = sh.u.p3.red[4]+sh.u.p3.red[5]+sh.u.p3.red[6]+sh.u.p3.red[7];
      sh.u.p3.al[tid] = pv / tot;
      __syncthreads();
      float a0=0.f, a1=0.f, a2=0.f, a3=0.f;
      const u16* vb = vuu + ((size_t)(b*256) + w*64)*1024 + jq*256 + lane*4;
      for (int s2=0; s2<64; s2++){
        float aa = sh.u.p3.al[w*64 + s2];
        ushort4 v = *(const ushort4*)(vb + (size_t)s2*1024);
        a0 += aa*us2f(v.x); a1 += aa*us2f(v.y); a2 += aa*us2f(v.z); a3 += aa*us2f(v.w);
      }
      float4 o4; o4.x=a0; o4.y=a1; o4.z=a2; o4.w=a3;
      *(float4*)(&sh.u.p3.pared[w][lane*4]) = o4;
      __syncthreads();
      if (tid < 64){
        const int col = tid*4;
        u16 his[4], los[4];
#pragma unroll
        for (int i=0;i<4;i++){
          float pa = sh.u.p3.pared[0][col+i] + sh.u.p3.pared[1][col+i]
                   + sh.u.p3.pared[2][col+i] + sh.u.p3.pared[3][col+i];
          pa += phB[(size_t)b*1024 + jq*256 + col + i];
          float o = tanhf(pa);
          split2(o, his[i], los[i]);
        }
        ushort4 vh; vh.x=his[0]; vh.y=his[1]; vh.z=his[2]; vh.w=his[3];
        ushort4 vl; vl.x=los[0]; vl.y=los[1]; vl.z=los[2]; vl.w=los[3];
        *(ushort4*)(ohi + (size_t)b*1024 + jq*256 + col) = vh;
        *(ushort4*)(olo + (size_t)b*1024 + jq*256 + col) = vl;
        *(ushort4*)(comb + (size_t)(t*64 + b)*1024 + jq*256 + col) = vh;
      }
    }
    gbar(cnt, (u32)(t*3 + 3));
  }
}

// ---------------- vocab GEMM (bf16 in) + fused softmax partials ----------------
__global__ __launch_bounds__(256) void k_gemm16(
    const u16* __restrict__ A, const u16* __restrict__ Bm,
    const float* __restrict__ bias,
    float* __restrict__ pm, float* __restrict__ ps,
    float* __restrict__ gl, const int* __restrict__ ids)
{
  __shared__ SharedU sm;
  const int tid = threadIdx.x;
  const int lane = tid & 63, w = tid >> 6;
  const int wm = w >> 1, wn = w & 1;
  int lw = blockIdx.y * 250 + blockIdx.x;        // 16000
  int swz = (lw & 7)*2000 + (lw >> 3);
  const int n0 = (swz % 250) * 128, m0 = (swz / 250) * 128;
  f32x4 acc[4][4];
#pragma unroll
  for (int i=0;i<4;i++)
#pragma unroll
    for (int j=0;j<4;j++) acc[i][j] = (f32x4)(0.f);

  for (int k0 = 0; k0 < 1024; k0 += 64) {
    __syncthreads();
#pragma unroll
    for (int i=0;i<8;i++){
      int idx = i*256 + tid;
      int half = idx >> 10, id2 = idx & 1023;
      int r = id2 >> 3, c8 = (id2 & 7)*8;
      if (half == 0){
        int gm = m0 + r;
        u16x8 v = {0,0,0,0,0,0,0,0};
        if (gm < MROWS) v = *(const u16x8*)(A + (size_t)gm*1024 + k0 + c8);
        *(u16x8*)(&sm.st.a[r*72 + c8]) = v;
      } else {
        u16x8 v = *(const u16x8*)(Bm + (size_t)(n0 + r)*1024 + k0 + c8);
        *(u16x8*)(&sm.st.b[r*72 + c8]) = v;
      }
    }
    __syncthreads();
#pragma unroll
    for (int kk = 0; kk < 64; kk += 32) {
      bf16x8 af[4], bfr[4];
      int krow = kk + ((lane >> 4) << 3);
#pragma unroll
      for (int m4=0;m4<4;m4++)
        af[m4] = *(const bf16x8*)(&sm.st.a[(wm*64 + m4*16 + (lane & 15))*72 + krow]);
#pragma unroll
      for (int n4=0;n4<4;n4++)
        bfr[n4] = *(const bf16x8*)(&sm.st.b[(wn*64 + n4*16 + (lane & 15))*72 + krow]);
#pragma unroll
      for (int m4=0;m4<4;m4++)
#pragma unroll
        for (int n4=0;n4<4;n4++)
          acc[m4][n4] = __builtin_amdgcn_mfma_f32_16x16x32_bf16(af[m4], bfr[n4], acc[m4][n4], 0,0,0);
    }
  }
  __syncthreads();
#pragma unroll
  for (int m4=0;m4<4;m4++)
#pragma unroll
    for (int n4=0;n4<4;n4++)
#pragma unroll
      for (int i=0;i<4;i++){
        int row = wm*64 + m4*16 + ((lane>>4)<<2) + i;
        int col = wn*64 + n4*16 + (lane&15);
        sm.cc[row*128 + col] = acc[m4][n4][i];
      }
  __syncthreads();

  if (tid < 128) {
    int row = tid, gm = m0 + row;
    if (gm < MROWS) {
      float mx = -1e30f;
      for (int j=0;j<128;j++){
        int col = (row + j) & 127;
        float x = sm.cc[row*128+col] + bias[n0+col];
        mx = fmaxf(mx, x);
      }
      float sum = 0.f;
      for (int j=0;j<128;j++){
        int col = (row + j) & 127;
        float x = sm.cc[row*128+col] + bias[n0+col];
        sum += expf(x - mx);
      }
      pm[(size_t)gm*NVB + n0/128] = mx;
      ps[(size_t)gm*NVB + n0/128] = sum;
      int g = ids[gm + 64];
      unsigned d = (unsigned)(g - n0);
      if (d < 128u) gl[gm] = sm.cc[row*128 + (int)d] + bias[g];
    }
  }
}

// ---------------- final reduce ----------------
__global__ void k_reduce(const float* __restrict__ pm, const float* __restrict__ ps,
                         const float* __restrict__ gl, const int* __restrict__ ids,
                         float* __restrict__ out)
{
  int b = blockIdx.x, tid = threadIdx.x;
  int lane = tid & 63, w = tid >> 6;
  __shared__ float wacc[4];
  float accum = 0.f;
  for (int t = w; t < TSTEPS; t += 4) {
    int r = t*64 + b;
    const float* pmr = pm + (size_t)r*NVB;
    const float* psr = ps + (size_t)r*NVB;
    float mx = -1e30f;
    for (int p2 = lane; p2 < NVB; p2 += 64) mx = fmaxf(mx, pmr[p2]);
#pragma unroll
    for (int off=32; off; off>>=1) mx = fmaxf(mx, __shfl_xor(mx, off));
    float sm = 0.f;
    for (int p2 = lane; p2 < NVB; p2 += 64) sm += psr[p2] * expf(pmr[p2] - mx);
#pragma unroll
    for (int off=32; off; off>>=1) sm += __shfl_xor(sm, off);
    if (lane == 0) {
      int g = ids[r + 64];
      if (g != 0) accum += gl[r] - (mx + logf(sm));
    }
  }
  if (lane == 0) wacc[w] = accum;
  __syncthreads();
  if (tid == 0) out[b] = wacc[0]+wacc[1]+wacc[2]+wacc[3];
}

// ---------------- host ----------------
extern "C" void kernel_launch(void* const* d_in, const int* in_sizes, int n_in,
                              void* d_out, int out_size, void* d_ws, size_t ws_size,
                              hipStream_t stream)
{
  const int*   ids  = (const int*)d_in[0];
  const float* vc   = (const float*)d_in[1];
  const float* h0   = (const float*)d_in[2];
  const float* c0   = (const float*)d_in[3];
  const float* Etgt = (const float*)d_in[4];
  const float* Watt = (const float*)d_in[5];
  const float* batt = (const float*)d_in[6];
  const float* Wih  = (const float*)d_in[7];
  const float* Whh  = (const float*)d_in[8];
  const float* Wu   = (const float*)d_in[9];
  const float* Wv   = (const float*)d_in[10];
  const float* bv   = (const float*)d_in[11];
  float* out = (float*)d_out;

  char* p = (char*)d_ws;
  auto alloc = [&](size_t bytes)->char* {
    char* r = p; p += (bytes + 255) & ~(size_t)255; return r;
  };
  u32* cnt   = (u32*)alloc(32768);               // 256 flags x 128B
  u16* Yh    = (u16*)alloc((size_t)8192*512*2);
  u16* Yl    = (u16*)alloc((size_t)8192*512*2);
  u16* WYh   = (u16*)alloc((size_t)4096*512*2);
  u16* WYl   = (u16*)alloc((size_t)4096*512*2);
  u16* Wuhh  = (u16*)alloc((size_t)1024*1024*2);
  u16* Wuhl  = (u16*)alloc((size_t)1024*1024*2);
  float* Wcat= (float*)alloc((size_t)2048*2048*4);
  u16* ep    = (u16*)alloc((size_t)64*256*1024*2);
  u16* vuu   = (u16*)alloc((size_t)64*256*1024*2);
  u16* Wvb   = (u16*)alloc((size_t)32000*1024*2);
  u16* comb  = (u16*)alloc((size_t)8192*1024*2);
  float* gY  = (float*)alloc((size_t)8192*4096*4);
  u16* hhi   = (u16*)alloc((size_t)2*65536*2);
  u16* hlo   = (u16*)alloc((size_t)2*65536*2);
  u16* ohi   = (u16*)alloc(65536*2);
  u16* olo   = (u16*)alloc(65536*2);
  float* ebuf= (float*)alloc((size_t)64*256*4);
  float* phB = (float*)alloc((size_t)64*1024*4);
  float* pm  = (float*)alloc((size_t)MROWS*NVB*4);
  float* ps  = (float*)alloc((size_t)MROWS*NVB*4);
  float* gl  = (float*)alloc((size_t)MROWS*4);

  p_init<<<288, 256, 0, stream>>>(h0, hhi, hlo, ohi, olo, cnt);
  p_wcat<<<(2048*2048)/256, 256, 0, stream>>>(Watt, Wu, Wcat);
  p_wy<<<dim3(2, 4096), 256, 0, stream>>>(Wih, WYh, WYl);
  p_wuh<<<dim3(4, 1024), 256, 0, stream>>>(Wu, Wuhh, Wuhl);
  p_y<<<dim3(2, 8192), 256, 0, stream>>>(ids, Etgt, Yh, Yl);
  p_wv<<<(32000*1024)/256, 256, 0, stream>>>(Wv, Wvb);

  k_gemm32<<<dim3(16, 128), 256, 0, stream>>>(vc, Wcat, batt, ep, vuu);
  k_gy<<<dim3(32, 64), 256, 0, stream>>>(Yh, Yl, WYh, WYl, gY);

  k_loop<<<NBLK, 256, 0, stream>>>(Wih, Whh, c0, Wuhh, Wuhl, gY, ep, vuu,
                                   hhi, hlo, ohi, olo, ebuf, phB, comb, cnt);

  k_gemm16<<<dim3(NVB, 64), 256, 0, stream>>>(comb, Wvb, bv, pm, ps, gl, ids);
  k_reduce<<<64, 256, 0, stream>>>(pm, ps, gl, ids, out);
}

// Round 6
// 13368.546 us; speedup vs baseline: 1.9095x; 1.2662x over previous
//
#include <hip/hip_runtime.h>
#include <hip/hip_bf16.h>

#define TSTEPS 127
#define NBLK 256
#define NVB 250      // 32000/128
#define MROWS 8128   // 127*64

typedef unsigned short u16;
typedef unsigned int u32;
typedef unsigned long long u64;
typedef _Float16 f16;
typedef __attribute__((ext_vector_type(8))) short bf16x8;
typedef __attribute__((ext_vector_type(8))) _Float16 f16x8;
typedef __attribute__((ext_vector_type(8))) unsigned short u16x8;
typedef __attribute__((ext_vector_type(4))) float f32x4;

__device__ __forceinline__ u16 f2h(float f){ f16 h=(f16)f; u16 r; __builtin_memcpy(&r,&h,2); return r; }
__device__ __forceinline__ float h2f(u16 u){ f16 h; __builtin_memcpy(&h,&u,2); return (float)h; }
__device__ __forceinline__ float us2f(u16 u){ union{float f;u32 i;}v; v.i=(u32)u<<16; return v.f; }
__device__ __forceinline__ u16 f2us(float f){ __hip_bfloat16 h=__float2bfloat16(f); u16 r; __builtin_memcpy(&r,&h,2); return r; }
__device__ __forceinline__ void split2(float x, u16& hi, u16& lo){
  u16 h = f2us(x); lo = f2us(x - us2f(h)); hi = h;
}

// ---- agent-scope (cache-bypassing) relaxed atomics for mutable shared state ----
__device__ __forceinline__ u64 ldg64(const u64* p){
  return __hip_atomic_load((u64*)p, __ATOMIC_RELAXED, __HIP_MEMORY_SCOPE_AGENT);
}
__device__ __forceinline__ float ldgf(const float* p){
  return __hip_atomic_load((float*)p, __ATOMIC_RELAXED, __HIP_MEMORY_SCOPE_AGENT);
}
__device__ __forceinline__ void stg64(u64* p, u64 v){
  __hip_atomic_store(p, v, __ATOMIC_RELAXED, __HIP_MEMORY_SCOPE_AGENT);
}
__device__ __forceinline__ void stg32(u32* p, u32 v){
  __hip_atomic_store(p, v, __ATOMIC_RELAXED, __HIP_MEMORY_SCOPE_AGENT);
}
__device__ __forceinline__ void stgf(float* p, float v){
  __hip_atomic_store(p, v, __ATOMIC_RELAXED, __HIP_MEMORY_SCOPE_AGENT);
}
__device__ __forceinline__ f16x8 mk8h(u64 a, u64 b){
  union { u64 q[2]; f16x8 v; } u; u.q[0]=a; u.q[1]=b; return u.v;
}

// flag-array barrier, NO acquire/invalidate (all mutable data is bypass-routed)
__device__ __forceinline__ void gbar(u32* flags, u32 token){
  asm volatile("s_waitcnt vmcnt(0) lgkmcnt(0)" ::: "memory");
  __syncthreads();
  if (threadIdx.x == 0)
    __hip_atomic_store(&flags[blockIdx.x*32], token, __ATOMIC_RELAXED, __HIP_MEMORY_SCOPE_AGENT);
  u32* myf = &flags[threadIdx.x*32];
  while (__hip_atomic_load(myf, __ATOMIC_RELAXED, __HIP_MEMORY_SCOPE_AGENT) < token)
    __builtin_amdgcn_s_sleep(1);
  __syncthreads();
}

// ---------------- prep kernels ----------------
__global__ void p_wcat(const float* __restrict__ Watt, const float* __restrict__ Wu,
                       float* __restrict__ Wcat){
  int idx = blockIdx.x*256 + threadIdx.x;      // 2048*2048
  int n = idx >> 11, k = idx & 2047;
  Wcat[idx] = (n < 1024) ? Watt[idx] : Wu[(size_t)(n-1024)*3072 + k];
}

// WY: Y-part of Wih in j'-order (j' = jj*4+g, j = g*1024+jj), split hi/lo (for k_gy)
__global__ void p_wy(const float* __restrict__ Wih, u16* __restrict__ WYh, u16* __restrict__ WYl){
  int k = blockIdx.x*256 + threadIdx.x;        // 512
  int rp = blockIdx.y;                         // 4096
  int j = (rp & 3)*1024 + (rp >> 2);
  float v = Wih[(size_t)j*1536 + 1024 + k];
  u16 hi, lo; split2(v, hi, lo);
  WYh[(size_t)rp*512 + k] = hi; WYl[(size_t)rp*512 + k] = lo;
}

__global__ void p_wuh(const float* __restrict__ Wu, u16* __restrict__ Wh){
  int k = blockIdx.x*256 + threadIdx.x;        // 1024
  int j = blockIdx.y;                          // 1024
  Wh[(size_t)j*1024 + k] = f2h(Wu[(size_t)j*3072 + 2048 + k]);
}

__global__ void p_y(const int* __restrict__ ids, const float* __restrict__ Etgt,
                    u16* __restrict__ Yh, u16* __restrict__ Yl){
  int e0 = blockIdx.x*256 + threadIdx.x;       // 512
  int row = blockIdx.y;                        // 8192
  int id = ids[row];
  float v = Etgt[(size_t)id*512 + e0];
  u16 hi, lo; split2(v, hi, lo);
  Yh[(size_t)row*512 + e0] = hi; Yl[(size_t)row*512 + e0] = lo;
}

__global__ void p_wv(const float* __restrict__ Wv, u16* __restrict__ Wvb){
  size_t idx = (size_t)blockIdx.x*256 + threadIdx.x;  // 32000*1024
  Wvb[idx] = f2h(Wv[idx]);
}

__global__ void p_init(const float* __restrict__ h0,
                       u16* __restrict__ hf, u16* __restrict__ of,
                       u32* __restrict__ flags){
  int idx = blockIdx.x*256 + threadIdx.x;
  if (idx < 65536){
    hf[idx] = f2h(h0[idx]);     // parity-0 buffer
    of[idx] = 0;
  } else if (idx < 65536 + 8192){
    flags[idx - 65536] = 0;
  }
}

// ---------------- enc_proj + Vu GEMM (fp32 in, f16 out): M=16384 N=2048 K=2048 ----
union SharedU {
  struct { u16 a[128*72]; u16 b[128*72]; } st;
  float cc[128*128];
};

__global__ __launch_bounds__(256) void k_gemm32(
    const float* __restrict__ A, const float* __restrict__ Bm,
    const float* __restrict__ bias, u16* __restrict__ ep, u16* __restrict__ vu)
{
  __shared__ SharedU sm;
  const int tid = threadIdx.x;
  const int lane = tid & 63, w = tid >> 6;
  const int wm = w >> 1, wn = w & 1;
  int lw = blockIdx.y * gridDim.x + blockIdx.x;       // 2048
  int swz = (lw & 7)*256 + (lw >> 3);
  const int n0 = (swz & 15) * 128, m0 = (swz >> 4) * 128;
  f32x4 acc[4][4];
#pragma unroll
  for (int i=0;i<4;i++)
#pragma unroll
    for (int j=0;j<4;j++) acc[i][j] = (f32x4)(0.f);

  for (int k0 = 0; k0 < 2048; k0 += 64) {
    __syncthreads();
#pragma unroll
    for (int i=0;i<8;i++){
      int idx = tid + i*256;
      int r = idx >> 4, c4 = idx & 15;
      float4 va = *(const float4*)(&A[(size_t)(m0+r)*2048 + k0 + c4*4]);
      ushort4 sa; sa.x=f2h(va.x); sa.y=f2h(va.y); sa.z=f2h(va.z); sa.w=f2h(va.w);
      *(ushort4*)(&sm.st.a[r*72 + c4*4]) = sa;
      float4 vb = *(const float4*)(&Bm[(size_t)(n0+r)*2048 + k0 + c4*4]);
      ushort4 sb; sb.x=f2h(vb.x); sb.y=f2h(vb.y); sb.z=f2h(vb.z); sb.w=f2h(vb.w);
      *(ushort4*)(&sm.st.b[r*72 + c4*4]) = sb;
    }
    __syncthreads();
#pragma unroll
    for (int kk = 0; kk < 64; kk += 32) {
      f16x8 af[4], bfr[4];
      int krow = kk + ((lane >> 4) << 3);
#pragma unroll
      for (int m4=0;m4<4;m4++)
        af[m4] = *(const f16x8*)(&sm.st.a[(wm*64 + m4*16 + (lane & 15))*72 + krow]);
#pragma unroll
      for (int n4=0;n4<4;n4++)
        bfr[n4] = *(const f16x8*)(&sm.st.b[(wn*64 + n4*16 + (lane & 15))*72 + krow]);
#pragma unroll
      for (int m4=0;m4<4;m4++)
#pragma unroll
        for (int n4=0;n4<4;n4++)
          acc[m4][n4] = __builtin_amdgcn_mfma_f32_16x16x32_f16(af[m4], bfr[n4], acc[m4][n4], 0,0,0);
    }
  }
  __syncthreads();
#pragma unroll
  for (int m4=0;m4<4;m4++)
#pragma unroll
    for (int n4=0;n4<4;n4++)
#pragma unroll
      for (int i=0;i<4;i++){
        int row = wm*64 + m4*16 + ((lane>>4)<<2) + i;
        int col = wn*64 + n4*16 + (lane&15);
        sm.cc[row*128 + col] = acc[m4][n4][i];
      }
  __syncthreads();
  for (int idx = tid; idx < 128*128; idx += 256) {
    int row = idx >> 7, col = idx & 127;
    int gm = m0 + row, gn = n0 + col;
    float vv = sm.cc[idx];
    if (gn < 1024) { vv += bias[gn]; ep[(size_t)gm*1024 + gn] = f2h(vv); }
    else           { vu[(size_t)gm*1024 + (gn-1024)] = f2h(vv); }
  }
}

// ---------------- gY GEMM: gY[(t*64+b)][j'] = Y[t,b,:]·WY[j',:], split-bf16 ----
__global__ __launch_bounds__(256) void k_gy(
    const u16* __restrict__ Ah, const u16* __restrict__ Al,
    const u16* __restrict__ Bh, const u16* __restrict__ Bl,
    float* __restrict__ gY)
{
  __shared__ u16 sah[128*40], sal[128*40], sbh[128*40], sbl[128*40];
  const int tid = threadIdx.x;
  const int lane = tid & 63, w = tid >> 6;
  const int wm = w >> 1, wn = w & 1;
  const int l15 = lane & 15, q8 = (lane>>4)*8;
  int lw = blockIdx.y * gridDim.x + blockIdx.x;       // 2048
  int swz = (lw & 7)*256 + (lw >> 3);
  const int n0 = (swz & 31)*128, m0 = (swz >> 5)*128;
  f32x4 acc[4][4];
#pragma unroll
  for (int i=0;i<4;i++)
#pragma unroll
    for (int j=0;j<4;j++) acc[i][j] = (f32x4)(0.f);

  for (int k0 = 0; k0 < 512; k0 += 32){
    __syncthreads();
#pragma unroll
    for (int i=0;i<8;i++){
      int idx = i*256 + tid;          // 2048 = 4 mats x 512 u16x8
      int mat = idx >> 9, sub = idx & 511;
      int r = sub >> 2, c8 = (sub & 3)*8;
      const u16* src = (mat==0)?Ah:(mat==1)?Al:(mat==2)?Bh:Bl;
      size_t base = (mat<2 ? (size_t)(m0+r)*512 : (size_t)(n0+r)*512) + k0 + c8;
      u16x8 v = *(const u16x8*)(src + base);
      u16* dst = (mat==0)?sah:(mat==1)?sal:(mat==2)?sbh:sbl;
      *(u16x8*)(&dst[r*40 + c8]) = v;
    }
    __syncthreads();
    bf16x8 ah[4], al2[4], bh[4], bl2[4];
#pragma unroll
    for (int m4=0;m4<4;m4++){
      ah[m4]  = *(const bf16x8*)(&sah[(wm*64+m4*16+l15)*40 + q8]);
      al2[m4] = *(const bf16x8*)(&sal[(wm*64+m4*16+l15)*40 + q8]);
    }
#pragma unroll
    for (int n4=0;n4<4;n4++){
      bh[n4]  = *(const bf16x8*)(&sbh[(wn*64+n4*16+l15)*40 + q8]);
      bl2[n4] = *(const bf16x8*)(&sbl[(wn*64+n4*16+l15)*40 + q8]);
    }
#pragma unroll
    for (int m4=0;m4<4;m4++)
#pragma unroll
      for (int n4=0;n4<4;n4++){
        acc[m4][n4] = __builtin_amdgcn_mfma_f32_16x16x32_bf16(ah[m4],  bh[n4],  acc[m4][n4], 0,0,0);
        acc[m4][n4] = __builtin_amdgcn_mfma_f32_16x16x32_bf16(al2[m4], bh[n4],  acc[m4][n4], 0,0,0);
        acc[m4][n4] = __builtin_amdgcn_mfma_f32_16x16x32_bf16(ah[m4],  bl2[n4], acc[m4][n4], 0,0,0);
      }
  }
#pragma unroll
  for (int m4=0;m4<4;m4++)
#pragma unroll
    for (int n4=0;n4<4;n4++)
#pragma unroll
      for (int i=0;i<4;i++){
        int gm = m0 + wm*64 + m4*16 + ((lane>>4)<<2) + i;
        int gn = n0 + wn*64 + n4*16 + l15;
        gY[(size_t)gm*4096 + gn] = acc[m4][n4][i];
      }
}

// ---------------- persistent recurrence kernel ----------------
// block = (jb = blk>>1 owns 32 j'-rows, bhalf = blk&1 owns 32 b's)
// waves: bsub = w&1 (16 b), khalf = w>>1 (k-half); LDS combine of k-halves.
struct LoopShared {
  u16 wg[32*2048];                       // f16 weights, byte ^= ((row&7)<<4)
  union {
    struct { float psum[2][64][8]; u32 hstage[32][4]; } p1;
    struct { float al[256]; float pared[4][256]; float red[8]; } p3;
  } u;
};

__global__ __launch_bounds__(256, 1) void k_loop(
    const float* __restrict__ Wih, const float* __restrict__ Whh,
    const float* __restrict__ c0g,
    const u16* __restrict__ Wuh16, const float* __restrict__ gY,
    const u16* __restrict__ ep, const u16* __restrict__ vuu,
    u16* __restrict__ hf, u16* __restrict__ of,
    float* __restrict__ ebuf, float* __restrict__ phB,
    u16* __restrict__ comb, u32* __restrict__ flags)
{
  __shared__ LoopShared sh;
  const int tid = threadIdx.x, blk = blockIdx.x;
  const int lane = tid & 63, w = tid >> 6;
  const int l15 = lane & 15, q = lane >> 4;
  const int jb = blk >> 1, bhalf = blk & 1;
  const int bsub = w & 1, khalf = w >> 1;
  const int b = bhalf*32 + bsub*16 + l15;

  // one-time: 32 j'-rows of [Wih_o | Whh] as f16 into LDS
  for (int i = tid; i < 32*512; i += 256){
    int r = i >> 9, c4 = i & 511;
    int jp = jb*32 + r;
    int j  = (jp & 3)*1024 + (jp >> 2);
    float4 v = (c4 < 256) ? *(const float4*)(&Wih[(size_t)j*1536 + c4*4])
                          : *(const float4*)(&Whh[(size_t)j*1024 + (c4-256)*4]);
    ushort4 hh; hh.x=f2h(v.x); hh.y=f2h(v.y); hh.z=f2h(v.z); hh.w=f2h(v.w);
    int byteoff = (r*4096 + c4*8) ^ ((r & 7) << 4);
    *(ushort4*)((char*)sh.wg + byteoff) = hh;
  }
  float cReg0 = 0.f, cReg1 = 0.f;
  if (w < 2){
    cReg0 = c0g[(size_t)b*1024 + jb*8 + q];
    cReg1 = c0g[(size_t)b*1024 + jb*8 + 4 + q];
  }
  __syncthreads();
  const char* wgc = (const char*)sh.wg;

  for (int t = 0; t < TSTEPS; ++t){
    const int p = t & 1;
    const u16* hP = hf + p*65536;
    u16* hN = hf + (p^1)*65536;

    // ======== P1: gates MFMA (f16, LDS weights) + LSTM ========
    {
      float4 gyv0, gyv1;
      if (w < 2){
        const float* gb = gY + ((size_t)(t*64 + b))*4096 + jb*32 + q*4;
        gyv0 = *(const float4*)(gb);
        gyv1 = *(const float4*)(gb + 16);
      }
      const u64* xsrc = (khalf ? (const u64*)hP : (const u64*)of) + b*256;
      f32x4 acc0 = (f32x4)(0.f), acc1 = (f32x4)(0.f);
#pragma unroll 4
      for (int kt = 0; kt < 32; ++kt){
        int base = khalf*2048 + kt*64 + q*16;
        int w0 = (l15*4096 + base) ^ ((l15 & 7) << 4);
        f16x8 wf0 = *(const f16x8*)(wgc + w0);
        f16x8 wf1 = *(const f16x8*)(wgc + w0 + 65536);   // row+16, same (row&7)
        const u64* px = xsrc + kt*8 + q*2;
        f16x8 xf = mk8h(ldg64(px), ldg64(px+1));
        acc0 = __builtin_amdgcn_mfma_f32_16x16x32_f16(wf0, xf, acc0, 0,0,0);
        acc1 = __builtin_amdgcn_mfma_f32_16x16x32_f16(wf1, xf, acc1, 0,0,0);
      }
      if (w >= 2){
        float* ps_ = &sh.u.p1.psum[w-2][lane][0];
#pragma unroll
        for (int i=0;i<4;i++){ ps_[i] = acc0[i]; ps_[4+i] = acc1[i]; }
      }
      __syncthreads();
      if (w < 2){
        const float* ps_ = &sh.u.p1.psum[w][lane][0];
        u16 h0b, h1b;
        {
          float gi = acc0[0]+ps_[0]+gyv0.x, gf = acc0[1]+ps_[1]+gyv0.y;
          float gg = acc0[2]+ps_[2]+gyv0.z, go = acc0[3]+ps_[3]+gyv0.w;
          gi = 1.f/(1.f+expf(-gi)); gf = 1.f/(1.f+expf(-gf));
          gg = tanhf(gg);           go = 1.f/(1.f+expf(-go));
          float cn = gf*cReg0 + gi*gg; cReg0 = cn;
          h0b = f2h(go*tanhf(cn));
        }
        {
          float gi = acc1[0]+ps_[4]+gyv1.x, gf = acc1[1]+ps_[5]+gyv1.y;
          float gg = acc1[2]+ps_[6]+gyv1.z, go = acc1[3]+ps_[7]+gyv1.w;
          gi = 1.f/(1.f+expf(-gi)); gf = 1.f/(1.f+expf(-gf));
          gg = tanhf(gg);           go = 1.f/(1.f+expf(-go));
          float cn = gf*cReg1 + gi*gg; cReg1 = cn;
          h1b = f2h(go*tanhf(cn));
        }
        int bl = bsub*16 + l15;
        u16* hs = (u16*)sh.u.p1.hstage;
        hs[bl*8 + q] = h0b;
        hs[bl*8 + 4 + q] = h1b;
      }
      __syncthreads();
      if (tid < 128){
        int bl = tid >> 2, sub = tid & 3;
        u32 v = sh.u.p1.hstage[bl][sub];
        stg32((u32*)hN + (size_t)(bhalf*32 + bl)*512 + jb*4 + sub, v);
      }
    }
    gbar(flags, (u32)(t*3 + 1));

    // ======== P2: ph MFMA (blocks 0..15) | e_t (blocks 16..255) ========
    if (blk < 16){
      const int jrow = blk*64 + w*16 + l15;
      const u16* wp = Wuh16 + (size_t)jrow*1024;
      f32x4 pacc[4];
#pragma unroll
      for (int i=0;i<4;i++) pacc[i] = (f32x4)(0.f);
#pragma unroll 2
      for (int kt = 0; kt < 32; ++kt){
        f16x8 bfr = *(const f16x8*)(wp + kt*32 + q*8);
#pragma unroll
        for (int m=0;m<4;m++){
          const u64* px = (const u64*)hN + (size_t)(m*16+l15)*256 + kt*8 + q*2;
          f16x8 xf = mk8h(ldg64(px), ldg64(px+1));
          pacc[m] = __builtin_amdgcn_mfma_f32_16x16x32_f16(xf, bfr, pacc[m], 0,0,0);
        }
      }
#pragma unroll
      for (int m=0;m<4;m++)
#pragma unroll
        for (int i=0;i<4;i++){
          int bb = m*16 + q*4 + i;
          stgf(phB + (size_t)bb*1024 + jrow, pacc[m][i]);
        }
    } else {
      for (int u2 = blk - 16; u2 < 256; u2 += 240){
        const int ab = u2 >> 2, sl = u2 & 3;
        float hr[64];
        {
          const u64* hp = (const u64*)hN + (size_t)ab*256 + l15*16;
#pragma unroll
          for (int i=0;i<16;i++){
            union{u64 q_; u16 s[4];} uu; uu.q_ = ldg64(hp + i);
#pragma unroll
            for (int e=0;e<4;e++) hr[i*4+e] = h2f(uu.s[e]);
          }
        }
        const int rbase = sl*64 + w*16;
#pragma unroll
        for (int rg = 0; rg < 4; rg++){
          int s = rbase + rg*4 + q;
          const u16x8* row = (const u16x8*)(ep + ((size_t)(ab*256 + s))*1024 + l15*64);
          float a = 0.f;
#pragma unroll
          for (int j=0;j<8;j++){
            u16x8 v = row[j];
#pragma unroll
            for (int e=0;e<8;e++) a += h2f(v[e]) * hr[j*8+e];
          }
          a += __shfl_xor(a, 1); a += __shfl_xor(a, 2);
          a += __shfl_xor(a, 4); a += __shfl_xor(a, 8);
          if (l15 == 0) stgf(ebuf + ab*256 + s, a);
        }
      }
    }
    gbar(flags, (u32)(t*3 + 2));

    // ======== P3: softmax + pa + o_t (block = (ab, jq)) ========
    {
      const int ab = blk >> 2, jq = blk & 3;
      float x = ldgf(ebuf + ab*256 + tid);
      float m_ = x;
#pragma unroll
      for (int off=32; off; off>>=1) m_ = fmaxf(m_, __shfl_xor(m_, off));
      if (lane == 0) sh.u.p3.red[w] = m_;
      __syncthreads();
      m_ = fmaxf(fmaxf(sh.u.p3.red[0],sh.u.p3.red[1]), fmaxf(sh.u.p3.red[2],sh.u.p3.red[3]));
      float pv = expf(x - m_);
      float sv = pv;
#pragma unroll
      for (int off=32; off; off>>=1) sv += __shfl_xor(sv, off);
      if (lane == 0) sh.u.p3.red[4+w] = sv;
      __syncthreads();
      float tot = sh.u.p3.red[4]+sh.u.p3.red[5]+sh.u.p3.red[6]+sh.u.p3.red[7];
      sh.u.p3.al[tid] = pv / tot;
      __syncthreads();
      float a0=0.f, a1=0.f, a2=0.f, a3=0.f;
      const u16* vb = vuu + ((size_t)(ab*256) + w*64)*1024 + jq*256 + lane*4;
      for (int s2=0; s2<64; s2++){
        float aa = sh.u.p3.al[w*64 + s2];
        ushort4 v = *(const ushort4*)(vb + (size_t)s2*1024);
        a0 += aa*h2f(v.x); a1 += aa*h2f(v.y); a2 += aa*h2f(v.z); a3 += aa*h2f(v.w);
      }
      float4 o4; o4.x=a0; o4.y=a1; o4.z=a2; o4.w=a3;
      *(float4*)(&sh.u.p3.pared[w][lane*4]) = o4;
      __syncthreads();
      if (tid < 64){
        const int col = tid*4;
        union{u64 q_; u16 s[4];} uo;
        ushort4 cw;
#pragma unroll
        for (int i=0;i<4;i++){
          float pa = sh.u.p3.pared[0][col+i] + sh.u.p3.pared[1][col+i]
                   + sh.u.p3.pared[2][col+i] + sh.u.p3.pared[3][col+i];
          pa += ldgf(phB + (size_t)ab*1024 + jq*256 + col + i);
          u16 ob = f2h(tanhf(pa));
          uo.s[i] = ob; (&cw.x)[i] = ob;
        }
        stg64((u64*)of + (size_t)ab*256 + jq*64 + tid, uo.q_);
        *(ushort4*)(comb + (size_t)(t*64 + ab)*1024 + jq*256 + col) = cw;
      }
    }
    gbar(flags, (u32)(t*3 + 3));
  }
}

// ---------------- vocab GEMM (f16 in) + fused softmax partials ----------------
__global__ __launch_bounds__(256) void k_gemm16(
    const u16* __restrict__ A, const u16* __restrict__ Bm,
    const float* __restrict__ bias,
    float* __restrict__ pm, float* __restrict__ ps,
    float* __restrict__ gl, const int* __restrict__ ids)
{
  __shared__ SharedU sm;
  const int tid = threadIdx.x;
  const int lane = tid & 63, w = tid >> 6;
  const int wm = w >> 1, wn = w & 1;
  int lw = blockIdx.y * 250 + blockIdx.x;        // 16000
  int swz = (lw & 7)*2000 + (lw >> 3);
  const int n0 = (swz % 250) * 128, m0 = (swz / 250) * 128;
  f32x4 acc[4][4];
#pragma unroll
  for (int i=0;i<4;i++)
#pragma unroll
    for (int j=0;j<4;j++) acc[i][j] = (f32x4)(0.f);

  for (int k0 = 0; k0 < 1024; k0 += 64) {
    __syncthreads();
#pragma unroll
    for (int i=0;i<8;i++){
      int idx = i*256 + tid;
      int half = idx >> 10, id2 = idx & 1023;
      int r = id2 >> 3, c8 = (id2 & 7)*8;
      if (half == 0){
        int gm = m0 + r;
        u16x8 v = {0,0,0,0,0,0,0,0};
        if (gm < MROWS) v = *(const u16x8*)(A + (size_t)gm*1024 + k0 + c8);
        *(u16x8*)(&sm.st.a[r*72 + c8]) = v;
      } else {
        u16x8 v = *(const u16x8*)(Bm + (size_t)(n0 + r)*1024 + k0 + c8);
        *(u16x8*)(&sm.st.b[r*72 + c8]) = v;
      }
    }
    __syncthreads();
#pragma unroll
    for (int kk = 0; kk < 64; kk += 32) {
      f16x8 af[4], bfr[4];
      int krow = kk + ((lane >> 4) << 3);
#pragma unroll
      for (int m4=0;m4<4;m4++)
        af[m4] = *(const f16x8*)(&sm.st.a[(wm*64 + m4*16 + (lane & 15))*72 + krow]);
#pragma unroll
      for (int n4=0;n4<4;n4++)
        bfr[n4] = *(const f16x8*)(&sm.st.b[(wn*64 + n4*16 + (lane & 15))*72 + krow]);
#pragma unroll
      for (int m4=0;m4<4;m4++)
#pragma unroll
        for (int n4=0;n4<4;n4++)
          acc[m4][n4] = __builtin_amdgcn_mfma_f32_16x16x32_f16(af[m4], bfr[n4], acc[m4][n4], 0,0,0);
    }
  }
  __syncthreads();
#pragma unroll
  for (int m4=0;m4<4;m4++)
#pragma unroll
    for (int n4=0;n4<4;n4++)
#pragma unroll
      for (int i=0;i<4;i++){
        int row = wm*64 + m4*16 + ((lane>>4)<<2) + i;
        int col = wn*64 + n4*16 + (lane&15);
        sm.cc[row*128 + col] = acc[m4][n4][i];
      }
  __syncthreads();

  if (tid < 128) {
    int row = tid, gm = m0 + row;
    if (gm < MROWS) {
      float mx = -1e30f;
      for (int j=0;j<128;j++){
        int col = (row + j) & 127;
        float x = sm.cc[row*128+col] + bias[n0+col];
        mx = fmaxf(mx, x);
      }
      float sum = 0.f;
      for (int j=0;j<128;j++){
        int col = (row + j) & 127;
        float x = sm.cc[row*128+col] + bias[n0+col];
        sum += expf(x - mx);
      }
      pm[(size_t)gm*NVB + n0/128] = mx;
      ps[(size_t)gm*NVB + n0/128] = sum;
      int g = ids[gm + 64];
      unsigned d = (unsigned)(g - n0);
      if (d < 128u) gl[gm] = sm.cc[row*128 + (int)d] + bias[g];
    }
  }
}

// ---------------- final reduce ----------------
__global__ void k_reduce(const float* __restrict__ pm, const float* __restrict__ ps,
                         const float* __restrict__ gl, const int* __restrict__ ids,
                         float* __restrict__ out)
{
  int b = blockIdx.x, tid = threadIdx.x;
  int lane = tid & 63, w = tid >> 6;
  __shared__ float wacc[4];
  float accum = 0.f;
  for (int t = w; t < TSTEPS; t += 4) {
    int r = t*64 + b;
    const float* pmr = pm + (size_t)r*NVB;
    const float* psr = ps + (size_t)r*NVB;
    float mx = -1e30f;
    for (int p2 = lane; p2 < NVB; p2 += 64) mx = fmaxf(mx, pmr[p2]);
#pragma unroll
    for (int off=32; off; off>>=1) mx = fmaxf(mx, __shfl_xor(mx, off));
    float sm = 0.f;
    for (int p2 = lane; p2 < NVB; p2 += 64) sm += psr[p2] * expf(pmr[p2] - mx);
#pragma unroll
    for (int off=32; off; off>>=1) sm += __shfl_xor(sm, off);
    if (lane == 0) {
      int g = ids[r + 64];
      if (g != 0) accum += gl[r] - (mx + logf(sm));
    }
  }
  if (lane == 0) wacc[w] = accum;
  __syncthreads();
  if (tid == 0) out[b] = wacc[0]+wacc[1]+wacc[2]+wacc[3];
}

// ---------------- host ----------------
extern "C" void kernel_launch(void* const* d_in, const int* in_sizes, int n_in,
                              void* d_out, int out_size, void* d_ws, size_t ws_size,
                              hipStream_t stream)
{
  const int*   ids  = (const int*)d_in[0];
  const float* vc   = (const float*)d_in[1];
  const float* h0   = (const float*)d_in[2];
  const float* c0   = (const float*)d_in[3];
  const float* Etgt = (const float*)d_in[4];
  const float* Watt = (const float*)d_in[5];
  const float* batt = (const float*)d_in[6];
  const float* Wih  = (const float*)d_in[7];
  const float* Whh  = (const float*)d_in[8];
  const float* Wu   = (const float*)d_in[9];
  const float* Wv   = (const float*)d_in[10];
  const float* bv   = (const float*)d_in[11];
  float* out = (float*)d_out;

  char* p = (char*)d_ws;
  auto alloc = [&](size_t bytes)->char* {
    char* r = p; p += (bytes + 255) & ~(size_t)255; return r;
  };
  u32* flags = (u32*)alloc(32768);
  u16* Yh    = (u16*)alloc((size_t)8192*512*2);
  u16* Yl    = (u16*)alloc((size_t)8192*512*2);
  u16* WYh   = (u16*)alloc((size_t)4096*512*2);
  u16* WYl   = (u16*)alloc((size_t)4096*512*2);
  u16* Wuh16 = (u16*)alloc((size_t)1024*1024*2);
  float* Wcat= (float*)alloc((size_t)2048*2048*4);
  u16* ep    = (u16*)alloc((size_t)64*256*1024*2);
  u16* vuu   = (u16*)alloc((size_t)64*256*1024*2);
  u16* Wvb   = (u16*)alloc((size_t)32000*1024*2);
  u16* comb  = (u16*)alloc((size_t)8192*1024*2);
  float* gY  = (float*)alloc((size_t)8192*4096*4);
  u16* hfbuf = (u16*)alloc((size_t)2*65536*2);
  u16* ofbuf = (u16*)alloc(65536*2);
  float* ebuf= (float*)alloc((size_t)64*256*4);
  float* phB = (float*)alloc((size_t)64*1024*4);
  float* pm  = (float*)alloc((size_t)MROWS*NVB*4);
  float* ps  = (float*)alloc((size_t)MROWS*NVB*4);
  float* gl  = (float*)alloc((size_t)MROWS*4);

  p_init<<<288, 256, 0, stream>>>(h0, hfbuf, ofbuf, flags);
  p_wcat<<<(2048*2048)/256, 256, 0, stream>>>(Watt, Wu, Wcat);
  p_wy<<<dim3(2, 4096), 256, 0, stream>>>(Wih, WYh, WYl);
  p_wuh<<<dim3(4, 1024), 256, 0, stream>>>(Wu, Wuh16);
  p_y<<<dim3(2, 8192), 256, 0, stream>>>(ids, Etgt, Yh, Yl);
  p_wv<<<(32000*1024)/256, 256, 0, stream>>>(Wv, Wvb);

  k_gemm32<<<dim3(16, 128), 256, 0, stream>>>(vc, Wcat, batt, ep, vuu);
  k_gy<<<dim3(32, 64), 256, 0, stream>>>(Yh, Yl, WYh, WYl, gY);

  k_loop<<<NBLK, 256, 0, stream>>>(Wih, Whh, c0, Wuh16, gY, ep, vuu,
                                   hfbuf, ofbuf, ebuf, phB, comb, flags);

  k_gemm16<<<dim3(NVB, 64), 256, 0, stream>>>(comb, Wvb, bv, pm, ps, gl, ids);
  k_reduce<<<64, 256, 0, stream>>>(pm, ps, gl, ids, out);
}